// Round 3
// baseline (105.621 us; speedup 1.0000x reference)
//
#include <hip/hip_runtime.h>
#include <hip/hip_bf16.h>

// DETR Hungarian-matcher cost matrix:
//   C[n, m] = 5*L1(pbox_n, tbox_m) - softmax(logits_n)[label_m] - 2*GIoU(n, m)
// N = bs*nq = 14400 rows, M = 800 targets, NC = 256 classes.
// OUTPUT IS FP32 (reference returns jnp.float32; harness maps non-bf16 -> float*).
//
// One block per row n. Phase 1: 256-thread row softmax into LDS (NC == block
// size). Phase 2: each thread produces 4 consecutive m and stores one float4.

constexpr float EPS = 1e-7f;

__global__ __launch_bounds__(256) void matcher_kernel(
    const float* __restrict__ logits,   // [N, NC]
    const float* __restrict__ pboxes,   // [N, 4]  cxcywh
    const int*   __restrict__ labels,   // [M]
    const float* __restrict__ tboxes,   // [M, 4]  cxcywh
    float* __restrict__ out,            // [N, M]  fp32
    int M, int lbl_mask)
{
    const int n    = blockIdx.x;
    const int tid  = threadIdx.x;
    const int lane = tid & 63;
    const int wave = tid >> 6;

    __shared__ float s_prob[256];
    __shared__ float s_red[4];

    // ---------- Phase 1: softmax over logits[n, :], one class per thread ----
    const float x = logits[(size_t)n * 256 + tid];

    float mx = x;
    #pragma unroll
    for (int off = 32; off > 0; off >>= 1)
        mx = fmaxf(mx, __shfl_xor(mx, off, 64));
    if (lane == 0) s_red[wave] = mx;
    __syncthreads();
    mx = fmaxf(fmaxf(s_red[0], s_red[1]), fmaxf(s_red[2], s_red[3]));

    const float e = __expf(x - mx);

    float sum = e;
    #pragma unroll
    for (int off = 32; off > 0; off >>= 1)
        sum += __shfl_xor(sum, off, 64);
    __syncthreads();                 // all reads of s_red done before rewrite
    if (lane == 0) s_red[wave] = sum;
    __syncthreads();
    sum = (s_red[0] + s_red[1]) + (s_red[2] + s_red[3]);

    s_prob[tid] = e / sum;
    __syncthreads();

    // ---------- Phase 2: M costs for this row, 4 per thread (float4 store) --
    const float4 pb = reinterpret_cast<const float4*>(pboxes)[n];  // uniform
    const float ax1 = pb.x - 0.5f * pb.z, ay1 = pb.y - 0.5f * pb.w;
    const float ax2 = pb.x + 0.5f * pb.z, ay2 = pb.y + 0.5f * pb.w;
    const float area1 = (ax2 - ax1) * (ay2 - ay1);

    float* orow = out + (size_t)n * M;
    const int quarters = M >> 2;

    for (int item = tid; item < quarters; item += 256) {
        const int m0 = item * 4;
        float res[4];
        #pragma unroll
        for (int j = 0; j < 4; ++j) {
            const int m = m0 + j;
            const float4 tb = reinterpret_cast<const float4*>(tboxes)[m];
            const float prob = s_prob[labels[m] & lbl_mask];

            const float l1 = fabsf(pb.x - tb.x) + fabsf(pb.y - tb.y)
                           + fabsf(pb.z - tb.z) + fabsf(pb.w - tb.w);

            const float bx1 = tb.x - 0.5f * tb.z, by1 = tb.y - 0.5f * tb.w;
            const float bx2 = tb.x + 0.5f * tb.z, by2 = tb.y + 0.5f * tb.w;
            const float area2 = (bx2 - bx1) * (by2 - by1);

            float iw = fminf(ax2, bx2) - fmaxf(ax1, bx1);
            float ih = fminf(ay2, by2) - fmaxf(ay1, by1);
            iw = fmaxf(iw, 0.0f); ih = fmaxf(ih, 0.0f);
            const float inter = iw * ih;
            const float uni = area1 + area2 - inter;
            const float iou = inter / (uni + EPS);

            float cw = fmaxf(ax2, bx2) - fminf(ax1, bx1);
            float ch = fmaxf(ay2, by2) - fminf(ay1, by1);
            cw = fmaxf(cw, 0.0f); ch = fmaxf(ch, 0.0f);
            const float carea = cw * ch;

            const float giou = iou - (carea - uni) / (carea + EPS);
            res[j] = 5.0f * l1 - prob - 2.0f * giou;
        }
        float4 v = make_float4(res[0], res[1], res[2], res[3]);
        reinterpret_cast<float4*>(orow)[item] = v;
    }

    // generic tail for M % 4 != 0 (no-op for M = 800)
    for (int m = (quarters << 2) + tid; m < M; m += 256) {
        const float4 tb = reinterpret_cast<const float4*>(tboxes)[m];
        const float prob = s_prob[labels[m] & lbl_mask];
        const float l1 = fabsf(pb.x - tb.x) + fabsf(pb.y - tb.y)
                       + fabsf(pb.z - tb.z) + fabsf(pb.w - tb.w);
        const float bx1 = tb.x - 0.5f * tb.z, by1 = tb.y - 0.5f * tb.w;
        const float bx2 = tb.x + 0.5f * tb.z, by2 = tb.y + 0.5f * tb.w;
        const float area2 = (bx2 - bx1) * (by2 - by1);
        float iw = fmaxf(fminf(ax2, bx2) - fmaxf(ax1, bx1), 0.0f);
        float ih = fmaxf(fminf(ay2, by2) - fmaxf(ay1, by1), 0.0f);
        const float inter = iw * ih;
        const float uni = area1 + area2 - inter;
        const float iou = inter / (uni + EPS);
        float cw = fmaxf(fmaxf(ax2, bx2) - fminf(ax1, bx1), 0.0f);
        float ch = fmaxf(fmaxf(ay2, by2) - fminf(ay1, by1), 0.0f);
        const float carea = cw * ch;
        const float giou = iou - (carea - uni) / (carea + EPS);
        orow[m] = 5.0f * l1 - prob - 2.0f * giou;
    }
}

extern "C" void kernel_launch(void* const* d_in, const int* in_sizes, int n_in,
                              void* d_out, int out_size, void* d_ws, size_t ws_size,
                              hipStream_t stream) {
    const float* logits = (const float*)d_in[0];   // [N, NC] fp32
    const float* pboxes = (const float*)d_in[1];   // [N, 4]  fp32
    const int*   labels = (const int*)d_in[2];     // [M]     int32
    const float* tboxes = (const float*)d_in[3];   // [M, 4]  fp32

    const int N  = in_sizes[1] / 4;       // pred_boxes: 14400
    const int M  = in_sizes[2];           // 800
    const int NC = in_sizes[0] / N;       // 256
    // Softmax phase assumes NC == 256 (one class per thread). lbl_mask keeps
    // any label read inside s_prob[] bounds.
    const int lbl_mask = NC - 1;          // 255

    matcher_kernel<<<N, 256, 0, stream>>>(
        logits, pboxes, labels, tboxes, (float*)d_out, M, lbl_mask);
}

// Round 4
// 96.504 us; speedup vs baseline: 1.0945x; 1.0945x over previous
//
#include <hip/hip_runtime.h>
#include <hip/hip_bf16.h>

// DETR Hungarian-matcher cost matrix:
//   C[n, m] = 5*L1(pbox_n, tbox_m) - softmax(logits_n)[label_m] - 2*GIoU(n, m)
// N = bs*nq = 14400 rows, M = 800 targets, NC = 256 classes. Output fp32.
//
// One WAVE per row (4 rows per 256-thread block, grid = N/4):
//   Phase 1: wave-local softmax — float4 logits load (64 lanes x 4 classes),
//            shuffle reductions, probs -> this wave's 1 KB LDS slice.
//   Phase 2: each lane computes 4 consecutive m per iter (int4 labels +
//            4x float4 tboxes, L1-resident), float4 store.
// Divides replaced by v_rcp_f32 (__builtin_amdgcn_rcpf): abs error budget is
// 0.4 (2% of max|C|~20); rcp's ~1ulp relative error is ~1e-6 here.

constexpr float EPS = 1e-7f;

__global__ __launch_bounds__(256) void matcher_kernel(
    const float* __restrict__ logits,   // [N, 256]
    const float* __restrict__ pboxes,   // [N, 4]  cxcywh
    const int*   __restrict__ labels,   // [M]
    const float* __restrict__ tboxes,   // [M, 4]  cxcywh
    float* __restrict__ out,            // [N, M]  fp32
    int N, int M, int lbl_mask)
{
    const int wave = threadIdx.x >> 6;
    const int lane = threadIdx.x & 63;
    const int n    = blockIdx.x * 4 + wave;

    __shared__ float s_prob[4][256];

    if (n < N) {
        // ---------- Phase 1: wave-local softmax over 256 classes ----------
        const float4 lg =
            reinterpret_cast<const float4*>(logits)[(size_t)n * 64 + lane];

        float mx = fmaxf(fmaxf(lg.x, lg.y), fmaxf(lg.z, lg.w));
        #pragma unroll
        for (int off = 32; off > 0; off >>= 1)
            mx = fmaxf(mx, __shfl_xor(mx, off, 64));

        const float e0 = __expf(lg.x - mx);
        const float e1 = __expf(lg.y - mx);
        const float e2 = __expf(lg.z - mx);
        const float e3 = __expf(lg.w - mx);

        float s = (e0 + e1) + (e2 + e3);
        #pragma unroll
        for (int off = 32; off > 0; off >>= 1)
            s += __shfl_xor(s, off, 64);

        const float inv = __builtin_amdgcn_rcpf(s);
        reinterpret_cast<float4*>(&s_prob[wave][0])[lane] =
            make_float4(e0 * inv, e1 * inv, e2 * inv, e3 * inv);
    }
    __syncthreads();   // orders LDS write->read (also across the n>=N guard)
    if (n >= N) return;

    // ---------- Phase 2: M costs for row n, 4 per lane per iter ----------
    const float4 pb = reinterpret_cast<const float4*>(pboxes)[n];  // uniform/wave
    const float ax1 = pb.x - 0.5f * pb.z, ay1 = pb.y - 0.5f * pb.w;
    const float ax2 = pb.x + 0.5f * pb.z, ay2 = pb.y + 0.5f * pb.w;
    const float area1 = (ax2 - ax1) * (ay2 - ay1);

    const float* sp   = s_prob[wave];
    float*       orow = out + (size_t)n * M;
    const int items = M >> 2;

    for (int item = lane; item < items; item += 64) {
        const int4 lb = reinterpret_cast<const int4*>(labels)[item];
        const float4* tbp = reinterpret_cast<const float4*>(tboxes) + item * 4;
        const int ls[4] = {lb.x, lb.y, lb.z, lb.w};
        float res[4];
        #pragma unroll
        for (int j = 0; j < 4; ++j) {
            const float4 tb  = tbp[j];
            const float prob = sp[ls[j] & lbl_mask];

            const float l1 = fabsf(pb.x - tb.x) + fabsf(pb.y - tb.y)
                           + fabsf(pb.z - tb.z) + fabsf(pb.w - tb.w);

            const float bx1 = tb.x - 0.5f * tb.z, by1 = tb.y - 0.5f * tb.w;
            const float bx2 = tb.x + 0.5f * tb.z, by2 = tb.y + 0.5f * tb.w;
            const float area2 = tb.z * tb.w;

            const float iw = fmaxf(fminf(ax2, bx2) - fmaxf(ax1, bx1), 0.0f);
            const float ih = fmaxf(fminf(ay2, by2) - fmaxf(ay1, by1), 0.0f);
            const float inter = iw * ih;
            const float uni   = area1 + area2 - inter;
            const float iou   = inter * __builtin_amdgcn_rcpf(uni + EPS);

            // enclosing box: w,h >= 0 (boxes have nonneg extents), clip no-op
            const float cw = fmaxf(ax2, bx2) - fminf(ax1, bx1);
            const float ch = fmaxf(ay2, by2) - fminf(ay1, by1);
            const float carea = cw * ch;

            const float giou =
                iou - (carea - uni) * __builtin_amdgcn_rcpf(carea + EPS);
            res[j] = 5.0f * l1 - prob - 2.0f * giou;
        }
        reinterpret_cast<float4*>(orow)[item] =
            make_float4(res[0], res[1], res[2], res[3]);
    }

    // generic tail for M % 4 != 0 (no-op for M = 800)
    for (int m = (items << 2) + lane; m < M; m += 64) {
        const float4 tb  = reinterpret_cast<const float4*>(tboxes)[m];
        const float prob = sp[labels[m] & lbl_mask];
        const float l1 = fabsf(pb.x - tb.x) + fabsf(pb.y - tb.y)
                       + fabsf(pb.z - tb.z) + fabsf(pb.w - tb.w);
        const float bx1 = tb.x - 0.5f * tb.z, by1 = tb.y - 0.5f * tb.w;
        const float bx2 = tb.x + 0.5f * tb.z, by2 = tb.y + 0.5f * tb.w;
        const float area2 = tb.z * tb.w;
        const float iw = fmaxf(fminf(ax2, bx2) - fmaxf(ax1, bx1), 0.0f);
        const float ih = fmaxf(fminf(ay2, by2) - fmaxf(ay1, by1), 0.0f);
        const float inter = iw * ih;
        const float uni   = area1 + area2 - inter;
        const float iou   = inter * __builtin_amdgcn_rcpf(uni + EPS);
        const float cw = fmaxf(ax2, bx2) - fminf(ax1, bx1);
        const float ch = fmaxf(ay2, by2) - fminf(ay1, by1);
        const float carea = cw * ch;
        const float giou =
            iou - (carea - uni) * __builtin_amdgcn_rcpf(carea + EPS);
        orow[m] = 5.0f * l1 - prob - 2.0f * giou;
    }
}

extern "C" void kernel_launch(void* const* d_in, const int* in_sizes, int n_in,
                              void* d_out, int out_size, void* d_ws, size_t ws_size,
                              hipStream_t stream) {
    const float* logits = (const float*)d_in[0];   // [N, NC] fp32
    const float* pboxes = (const float*)d_in[1];   // [N, 4]  fp32
    const int*   labels = (const int*)d_in[2];     // [M]     int32
    const float* tboxes = (const float*)d_in[3];   // [M, 4]  fp32

    const int N  = in_sizes[1] / 4;       // pred_boxes: 14400
    const int M  = in_sizes[2];           // 800
    const int NC = in_sizes[0] / N;       // 256 (softmax assumes 256)
    const int lbl_mask = NC - 1;          // keeps gather inside s_prob

    const int grid = (N + 3) / 4;         // 4 rows (waves) per block
    matcher_kernel<<<grid, 256, 0, stream>>>(
        logits, pboxes, labels, tboxes, (float*)d_out, N, M, lbl_mask);
}

// Round 5
// 95.817 us; speedup vs baseline: 1.1023x; 1.0072x over previous
//
#include <hip/hip_runtime.h>
#include <hip/hip_bf16.h>

// DETR Hungarian-matcher cost matrix:
//   C[n, m] = 5*L1(pbox_n, tbox_m) - softmax(logits_n)[label_m] - 2*GIoU(n, m)
// N = bs*nq = 14400 rows, M = 800 targets, NC = 256 classes. Output fp32.
//
// Optimized path (NC==256, M==800): one wave per 4 rows, target boxes/labels
// staged ONCE into registers per wave (row-invariant!), so the per-pair inner
// loop touches memory only for the 1-word prob gather + the output store.
// Round-4 profiling model: per-row re-reads of tboxes through L1 (5 vector
// loads x ~64 cyc per item-iter) were ~23 us of the ~40 us kernel; registers
// remove that term entirely.
//
// rcp instead of IEEE div: abs error budget is 0.4 (2% of max|C|~20),
// v_rcp_f32 is ~1 ulp here.

constexpr float EPS = 1e-7f;

__device__ __forceinline__ float pair_cost(
    const float4& pb, float ax1, float ay1, float ax2, float ay2, float area1,
    const float4& tb, float prob)
{
    const float l1 = fabsf(pb.x - tb.x) + fabsf(pb.y - tb.y)
                   + fabsf(pb.z - tb.z) + fabsf(pb.w - tb.w);

    const float bx1 = tb.x - 0.5f * tb.z, by1 = tb.y - 0.5f * tb.w;
    const float bx2 = tb.x + 0.5f * tb.z, by2 = tb.y + 0.5f * tb.w;
    const float area2 = tb.z * tb.w;

    const float iw = fmaxf(fminf(ax2, bx2) - fmaxf(ax1, bx1), 0.0f);
    const float ih = fmaxf(fminf(ay2, by2) - fmaxf(ay1, by1), 0.0f);
    const float inter = iw * ih;
    const float uni   = area1 + area2 - inter;
    const float iou   = inter * __builtin_amdgcn_rcpf(uni + EPS);

    const float cw = fmaxf(ax2, bx2) - fminf(ax1, bx1);   // >= 0 by constr.
    const float ch = fmaxf(ay2, by2) - fminf(ay1, by1);
    const float carea = cw * ch;

    const float giou = iou - (carea - uni) * __builtin_amdgcn_rcpf(carea + EPS);
    return 5.0f * l1 - prob - 2.0f * giou;
}

// ---------------- optimized kernel: NC==256, M==800 ----------------
__global__ __launch_bounds__(256) void matcher_opt(
    const float* __restrict__ logits,   // [N, 256]
    const float* __restrict__ pboxes,   // [N, 4]  cxcywh
    const int*   __restrict__ labels,   // [800]
    const float* __restrict__ tboxes,   // [800, 4] cxcywh
    float* __restrict__ out,            // [N, 800]
    int N)
{
    const int wave = threadIdx.x >> 6;
    const int lane = threadIdx.x & 63;

    __shared__ float4 s_tb[800];
    __shared__ int    s_lb[800];
    __shared__ float  s_prob[4][256];

    // ---- cooperative coalesced staging of targets (once per block) ----
    for (int i = threadIdx.x; i < 800; i += 256) {
        s_tb[i] = reinterpret_cast<const float4*>(tboxes)[i];
        s_lb[i] = labels[i] & 255;       // mask keeps prob gather in-bounds
    }
    __syncthreads();                     // the only block barrier

    // ---- per-wave register copies: 3 uniform groups of 4 + half-wave tail --
    float4 tb[3][4];
    int    po[3][4];
    #pragma unroll
    for (int g = 0; g < 3; ++g) {
        const int m0 = (g * 64 + lane) * 4;
        #pragma unroll
        for (int j = 0; j < 4; ++j) {
            tb[g][j] = s_tb[m0 + j];
            po[g][j] = s_lb[m0 + j];
        }
    }
    float4 tbt = make_float4(0.f, 0.f, 0.f, 0.f);
    int pot = 0;
    if (lane < 32) { tbt = s_tb[768 + lane]; pot = s_lb[768 + lane]; }

    float* sp = s_prob[wave];            // wave-private slice

    const int n0 = (blockIdx.x * 4 + wave) * 4;   // 4 rows per wave
    #pragma unroll 1
    for (int r = 0; r < 4; ++r) {
        const int n = n0 + r;
        if (n >= N) return;

        // ---- softmax over 256 classes (pure wave-shuffle) ----
        const float4 lg =
            reinterpret_cast<const float4*>(logits)[(size_t)n * 64 + lane];
        float mx = fmaxf(fmaxf(lg.x, lg.y), fmaxf(lg.z, lg.w));
        #pragma unroll
        for (int off = 32; off > 0; off >>= 1)
            mx = fmaxf(mx, __shfl_xor(mx, off, 64));
        const float e0 = __expf(lg.x - mx), e1 = __expf(lg.y - mx);
        const float e2 = __expf(lg.z - mx), e3 = __expf(lg.w - mx);
        float s = (e0 + e1) + (e2 + e3);
        #pragma unroll
        for (int off = 32; off > 0; off >>= 1)
            s += __shfl_xor(s, off, 64);
        const float inv = __builtin_amdgcn_rcpf(s);
        reinterpret_cast<float4*>(sp)[lane] =
            make_float4(e0 * inv, e1 * inv, e2 * inv, e3 * inv);
        // wave-private LDS write->read: DS pipe is in-order per wave and the
        // compiler inserts lgkmcnt waits — no barrier needed.

        // ---- row constants ----
        const float4 pb = reinterpret_cast<const float4*>(pboxes)[n];
        const float ax1 = pb.x - 0.5f * pb.z, ay1 = pb.y - 0.5f * pb.w;
        const float ax2 = pb.x + 0.5f * pb.z, ay2 = pb.y + 0.5f * pb.w;
        const float area1 = pb.z * pb.w;

        float* orow = out + (size_t)n * 800;

        // ---- 768 targets: 3 uniform float4-store groups ----
        #pragma unroll
        for (int g = 0; g < 3; ++g) {
            float4 res;
            res.x = pair_cost(pb, ax1, ay1, ax2, ay2, area1, tb[g][0], sp[po[g][0]]);
            res.y = pair_cost(pb, ax1, ay1, ax2, ay2, area1, tb[g][1], sp[po[g][1]]);
            res.z = pair_cost(pb, ax1, ay1, ax2, ay2, area1, tb[g][2], sp[po[g][2]]);
            res.w = pair_cost(pb, ax1, ay1, ax2, ay2, area1, tb[g][3], sp[po[g][3]]);
            reinterpret_cast<float4*>(orow)[g * 64 + lane] = res;
        }
        // ---- last 32 targets: half-wave scalar tail ----
        if (lane < 32)
            orow[768 + lane] =
                pair_cost(pb, ax1, ay1, ax2, ay2, area1, tbt, sp[pot]);
    }
}

// ---------------- generic fallback (any NC multiple-of-4 >= 4, any M) ------
__global__ __launch_bounds__(256) void matcher_generic(
    const float* __restrict__ logits, const float* __restrict__ pboxes,
    const int* __restrict__ labels, const float* __restrict__ tboxes,
    float* __restrict__ out, int N, int M, int NC, int lbl_mask)
{
    const int wave = threadIdx.x >> 6;
    const int lane = threadIdx.x & 63;
    const int n    = blockIdx.x * 4 + wave;

    extern __shared__ float s_dyn[];           // [4][NC]
    float* sp = s_dyn + wave * NC;

    if (n < N) {
        float mx = -3.4e38f;
        for (int c = lane; c < NC; c += 64) mx = fmaxf(mx, logits[(size_t)n * NC + c]);
        #pragma unroll
        for (int off = 32; off > 0; off >>= 1) mx = fmaxf(mx, __shfl_xor(mx, off, 64));
        float s = 0.f;
        for (int c = lane; c < NC; c += 64) {
            const float e = __expf(logits[(size_t)n * NC + c] - mx);
            sp[c] = e; s += e;
        }
        #pragma unroll
        for (int off = 32; off > 0; off >>= 1) s += __shfl_xor(s, off, 64);
        const float inv = __builtin_amdgcn_rcpf(s);
        for (int c = lane; c < NC; c += 64) sp[c] *= inv;
    }
    __syncthreads();
    if (n >= N) return;

    const float4 pb = reinterpret_cast<const float4*>(pboxes)[n];
    const float ax1 = pb.x - 0.5f * pb.z, ay1 = pb.y - 0.5f * pb.w;
    const float ax2 = pb.x + 0.5f * pb.z, ay2 = pb.y + 0.5f * pb.w;
    const float area1 = pb.z * pb.w;
    float* orow = out + (size_t)n * M;

    for (int m = lane; m < M; m += 64) {
        const float4 tb = reinterpret_cast<const float4*>(tboxes)[m];
        orow[m] = pair_cost(pb, ax1, ay1, ax2, ay2, area1, tb,
                            sp[labels[m] & lbl_mask]);
    }
}

extern "C" void kernel_launch(void* const* d_in, const int* in_sizes, int n_in,
                              void* d_out, int out_size, void* d_ws, size_t ws_size,
                              hipStream_t stream) {
    const float* logits = (const float*)d_in[0];   // [N, NC] fp32
    const float* pboxes = (const float*)d_in[1];   // [N, 4]  fp32
    const int*   labels = (const int*)d_in[2];     // [M]     int32
    const float* tboxes = (const float*)d_in[3];   // [M, 4]  fp32

    const int N  = in_sizes[1] / 4;       // pred_boxes: 14400
    const int M  = in_sizes[2];           // 800
    const int NC = in_sizes[0] / N;       // 256

    if (NC == 256 && M == 800) {
        const int waves = (N + 3) / 4;    // 4 rows per wave
        const int grid  = (waves + 3) / 4;
        matcher_opt<<<grid, 256, 0, stream>>>(
            logits, pboxes, labels, tboxes, (float*)d_out, N);
    } else {
        int lbl_mask = 1; while (lbl_mask < NC) lbl_mask <<= 1;  // pow2 >= NC
        --lbl_mask;
        const int grid = (N + 3) / 4;
        matcher_generic<<<grid, 256, 4 * NC * sizeof(float), stream>>>(
            logits, pboxes, labels, tboxes, (float*)d_out, N, M, NC, lbl_mask);
    }
}

// Round 6
// 93.280 us; speedup vs baseline: 1.1323x; 1.0272x over previous
//
#include <hip/hip_runtime.h>
#include <hip/hip_bf16.h>

// DETR Hungarian-matcher cost matrix:
//   C[n, m] = 5*L1(pbox_n, tbox_m) - softmax(logits_n)[label_m] - 2*GIoU(n, m)
// N = bs*nq = 14400 rows, M = 800 targets, NC = 256 classes. Output fp32.
//
// R6: minimal-register-pressure variant to discriminate "at memory roofline"
// vs "VGPR/spill-bound". One wave per 4 rows. Targets staged once per block
// into LDS; phase 2 reads s_tb[m] with m = g*64+lane (lane stride 16 B ==
// the conflict-free ds_read_b128 pattern) and stores scalar dwords
// (64 lanes x 4 B = 256 B/instr, fully coalesced).
//
// rcp instead of IEEE div: abs error budget 0.4 (2% of max|C|~20).

constexpr float EPS = 1e-7f;

__device__ __forceinline__ float pair_cost(
    const float4& pb, float ax1, float ay1, float ax2, float ay2, float area1,
    const float4& tb, float prob)
{
    const float l1 = fabsf(pb.x - tb.x) + fabsf(pb.y - tb.y)
                   + fabsf(pb.z - tb.z) + fabsf(pb.w - tb.w);

    const float bx1 = tb.x - 0.5f * tb.z, by1 = tb.y - 0.5f * tb.w;
    const float bx2 = tb.x + 0.5f * tb.z, by2 = tb.y + 0.5f * tb.w;
    const float area2 = tb.z * tb.w;

    const float iw = fmaxf(fminf(ax2, bx2) - fmaxf(ax1, bx1), 0.0f);
    const float ih = fmaxf(fminf(ay2, by2) - fmaxf(ay1, by1), 0.0f);
    const float inter = iw * ih;
    const float uni   = area1 + area2 - inter;
    const float iou   = inter * __builtin_amdgcn_rcpf(uni + EPS);

    const float cw = fmaxf(ax2, bx2) - fminf(ax1, bx1);   // >= 0 by constr.
    const float ch = fmaxf(ay2, by2) - fminf(ay1, by1);
    const float carea = cw * ch;

    const float giou = iou - (carea - uni) * __builtin_amdgcn_rcpf(carea + EPS);
    return 5.0f * l1 - prob - 2.0f * giou;
}

// ---------------- optimized kernel: NC==256, M==800 ----------------
__global__ __launch_bounds__(256) void matcher_opt(
    const float* __restrict__ logits,   // [N, 256]
    const float* __restrict__ pboxes,   // [N, 4]  cxcywh
    const int*   __restrict__ labels,   // [800]
    const float* __restrict__ tboxes,   // [800, 4] cxcywh
    float* __restrict__ out,            // [N, 800]
    int N)
{
    const int wave = threadIdx.x >> 6;
    const int lane = threadIdx.x & 63;

    __shared__ float4 s_tb[800];
    __shared__ int    s_lb[800];
    __shared__ float  s_prob[4][256];

    // ---- cooperative coalesced staging of targets (once per block) ----
    for (int i = threadIdx.x; i < 800; i += 256) {
        s_tb[i] = reinterpret_cast<const float4*>(tboxes)[i];
        s_lb[i] = labels[i] & 255;       // mask keeps prob gather in-bounds
    }
    __syncthreads();                     // the only block barrier

    float* sp = s_prob[wave];            // wave-private slice

    const int n0 = (blockIdx.x * 4 + wave) * 4;   // 4 rows per wave
    #pragma unroll 1
    for (int r = 0; r < 4; ++r) {
        const int n = n0 + r;
        if (n >= N) return;

        // ---- softmax over 256 classes (pure wave-shuffle) ----
        const float4 lg =
            reinterpret_cast<const float4*>(logits)[(size_t)n * 64 + lane];
        float mx = fmaxf(fmaxf(lg.x, lg.y), fmaxf(lg.z, lg.w));
        #pragma unroll
        for (int off = 32; off > 0; off >>= 1)
            mx = fmaxf(mx, __shfl_xor(mx, off, 64));
        const float e0 = __expf(lg.x - mx), e1 = __expf(lg.y - mx);
        const float e2 = __expf(lg.z - mx), e3 = __expf(lg.w - mx);
        float s = (e0 + e1) + (e2 + e3);
        #pragma unroll
        for (int off = 32; off > 0; off >>= 1)
            s += __shfl_xor(s, off, 64);
        const float inv = __builtin_amdgcn_rcpf(s);
        reinterpret_cast<float4*>(sp)[lane] =
            make_float4(e0 * inv, e1 * inv, e2 * inv, e3 * inv);
        // wave-private LDS write->read: DS pipe is in-order per wave and the
        // compiler inserts lgkmcnt waits — no barrier needed.

        // ---- row constants ----
        const float4 pb = reinterpret_cast<const float4*>(pboxes)[n];
        const float ax1 = pb.x - 0.5f * pb.z, ay1 = pb.y - 0.5f * pb.w;
        const float ax2 = pb.x + 0.5f * pb.z, ay2 = pb.y + 0.5f * pb.w;
        const float area1 = pb.z * pb.w;

        float* orow = out + (size_t)n * 800;

        // ---- 768 targets: 12 full-wave iterations, conflict-free b128 ----
        #pragma unroll 4
        for (int m = lane; m < 768; m += 64) {
            const float4 tb = s_tb[m];
            orow[m] = pair_cost(pb, ax1, ay1, ax2, ay2, area1, tb, sp[s_lb[m]]);
        }
        // ---- last 32 targets: half-wave tail ----
        if (lane < 32) {
            const int m = 768 + lane;
            orow[m] = pair_cost(pb, ax1, ay1, ax2, ay2, area1, s_tb[m],
                                sp[s_lb[m]]);
        }
    }
}

// ---------------- generic fallback (any NC multiple-of-4 >= 4, any M) ------
__global__ __launch_bounds__(256) void matcher_generic(
    const float* __restrict__ logits, const float* __restrict__ pboxes,
    const int* __restrict__ labels, const float* __restrict__ tboxes,
    float* __restrict__ out, int N, int M, int NC, int lbl_mask)
{
    const int wave = threadIdx.x >> 6;
    const int lane = threadIdx.x & 63;
    const int n    = blockIdx.x * 4 + wave;

    extern __shared__ float s_dyn[];           // [4][NC]
    float* sp = s_dyn + wave * NC;

    if (n < N) {
        float mx = -3.4e38f;
        for (int c = lane; c < NC; c += 64) mx = fmaxf(mx, logits[(size_t)n * NC + c]);
        #pragma unroll
        for (int off = 32; off > 0; off >>= 1) mx = fmaxf(mx, __shfl_xor(mx, off, 64));
        float s = 0.f;
        for (int c = lane; c < NC; c += 64) {
            const float e = __expf(logits[(size_t)n * NC + c] - mx);
            sp[c] = e; s += e;
        }
        #pragma unroll
        for (int off = 32; off > 0; off >>= 1) s += __shfl_xor(s, off, 64);
        const float inv = __builtin_amdgcn_rcpf(s);
        for (int c = lane; c < NC; c += 64) sp[c] *= inv;
    }
    __syncthreads();
    if (n >= N) return;

    const float4 pb = reinterpret_cast<const float4*>(pboxes)[n];
    const float ax1 = pb.x - 0.5f * pb.z, ay1 = pb.y - 0.5f * pb.w;
    const float ax2 = pb.x + 0.5f * pb.z, ay2 = pb.y + 0.5f * pb.w;
    const float area1 = pb.z * pb.w;
    float* orow = out + (size_t)n * M;

    for (int m = lane; m < M; m += 64) {
        const float4 tb = reinterpret_cast<const float4*>(tboxes)[m];
        orow[m] = pair_cost(pb, ax1, ay1, ax2, ay2, area1, tb,
                            sp[labels[m] & lbl_mask]);
    }
}

extern "C" void kernel_launch(void* const* d_in, const int* in_sizes, int n_in,
                              void* d_out, int out_size, void* d_ws, size_t ws_size,
                              hipStream_t stream) {
    const float* logits = (const float*)d_in[0];   // [N, NC] fp32
    const float* pboxes = (const float*)d_in[1];   // [N, 4]  fp32
    const int*   labels = (const int*)d_in[2];     // [M]     int32
    const float* tboxes = (const float*)d_in[3];   // [M, 4]  fp32

    const int N  = in_sizes[1] / 4;       // pred_boxes: 14400
    const int M  = in_sizes[2];           // 800
    const int NC = in_sizes[0] / N;       // 256

    if (NC == 256 && M == 800) {
        const int waves = (N + 3) / 4;    // 4 rows per wave
        const int grid  = (waves + 3) / 4;
        matcher_opt<<<grid, 256, 0, stream>>>(
            logits, pboxes, labels, tboxes, (float*)d_out, N);
    } else {
        int lbl_mask = 1; while (lbl_mask < NC) lbl_mask <<= 1;  // pow2 >= NC
        --lbl_mask;
        const int grid = (N + 3) / 4;
        matcher_generic<<<grid, 256, 4 * NC * sizeof(float), stream>>>(
            logits, pboxes, labels, tboxes, (float*)d_out, N, M, NC, lbl_mask);
    }
}